// Round 1
// baseline (1508.819 us; speedup 1.0000x reference)
//
#include <hip/hip_runtime.h>
#include <math.h>

#define N_NODES 100000
#define K_NBRS 16
#define N_EDGES (N_NODES * K_NBRS)
#define TPB 256
#define NBLK 2048

// broadcast lane k's value of v to all lanes (k compile-time after unroll)
__device__ __forceinline__ float bcast(float v, int k) {
  return __int_as_float(__builtin_amdgcn_readlane(__float_as_int(v), k));
}

__global__ void k_zero_g(int* g) {
  if (threadIdx.x < 64) g[threadIdx.x] = 0;
}

// Normalize edge_index row 0 (src) to int32, handling either int32 or int64
// on-device (JAX x64 ambiguity). int64 little-endian: value e at words [2e,2e+1].
__global__ void k_normsrc(const int* __restrict__ ei, int* __restrict__ srcout) {
  const bool is64 = (ei[1] == 0) && (ei[3] == 0) && (ei[5] == 0) && (ei[7] == 0);
  const int tid = blockIdx.x * blockDim.x + threadIdx.x;
  const int stride = gridDim.x * blockDim.x;
  for (int e = tid; e < N_EDGES; e += stride)
    srcout[e] = is64 ? ei[2 * e] : ei[e];
}

// Layer 1: A = x @ (W1_top - W1_bot) + b1 ; B = x @ W1_bot  (C_in = 3)
__global__ void k_layer1(const float* __restrict__ x, const float* __restrict__ W1,
                         const float* __restrict__ b1,
                         float* __restrict__ A, float* __restrict__ B) {
  const int lane = threadIdx.x & 63;
  const int nwaves = (gridDim.x * blockDim.x) >> 6;
  const int wid0 = (blockIdx.x * blockDim.x + threadIdx.x) >> 6;
  float w[6];
#pragma unroll
  for (int k = 0; k < 6; ++k) w[k] = W1[k * 64 + lane];
  const float bias = b1[lane];
  for (int i0 = wid0; i0 < N_NODES; i0 += nwaves) {
    const int i = __builtin_amdgcn_readfirstlane(i0);
    const float x0 = x[3 * i], x1 = x[3 * i + 1], x2 = x[3 * i + 2];
    const float b = fmaf(x0, w[3], fmaf(x1, w[4], x2 * w[5]));
    const float a = bias + fmaf(x0, w[0] - w[3],
                          fmaf(x1, w[1] - w[4], x2 * (w[2] - w[5])));
    A[(size_t)i * 64 + lane] = a;
    B[(size_t)i * 64 + lane] = b;
  }
}

// Aggregation h[i] = max_{e<16} relu(A[i] + B[src[i*16+e]]), fused with the
// NEXT layer's node-GEMM: Aout = h @ (Wn_top - Wn_bot) + bn ; Bout = h @ Wn_bot.
// Last layer instead writes h and accumulates the global max into g.
template <bool DO_GEMM, bool DO_GMAX>
__global__ void k_layer(const int* __restrict__ src,
                        const float* __restrict__ Ain, const float* __restrict__ Bin,
                        const float* __restrict__ Wn, const float* __restrict__ bn,
                        float* __restrict__ Aout, float* __restrict__ Bout,
                        int* __restrict__ g) {
  const int lane = threadIdx.x & 63;
  const int nwaves = (gridDim.x * blockDim.x) >> 6;
  const int wid0 = (blockIdx.x * blockDim.x + threadIdx.x) >> 6;
  float wA[64], wB[64];
  float bias = 0.f;
  if constexpr (DO_GEMM) {
#pragma unroll
    for (int k = 0; k < 64; ++k) {
      const float wt = Wn[k * 64 + lane];
      const float wb = Wn[(64 + k) * 64 + lane];
      wA[k] = wt - wb;
      wB[k] = wb;
    }
    bias = bn[lane];
  }
  float gm = 0.f;
  for (int i0 = wid0; i0 < N_NODES; i0 += nwaves) {
    const int i = __builtin_amdgcn_readfirstlane(i0);
    const float a = Ain[(size_t)i * 64 + lane];
    const int* sp = src + i * K_NBRS;
    float m = 0.f;  // relu output >= 0 and every node has exactly 16 edges
#pragma unroll
    for (int e = 0; e < K_NBRS; ++e) {
      const int j = sp[e];
      const float bv = Bin[(size_t)j * 64 + lane];
      m = fmaxf(m, fmaxf(a + bv, 0.f));
    }
    if constexpr (DO_GEMM) {
      float acc_a = bias, acc_b = 0.f;
#pragma unroll
      for (int k = 0; k < 64; ++k) {
        const float hk = bcast(m, k);
        acc_a = fmaf(hk, wA[k], acc_a);
        acc_b = fmaf(hk, wB[k], acc_b);
      }
      Aout[(size_t)i * 64 + lane] = acc_a;
      Bout[(size_t)i * 64 + lane] = acc_b;
    } else {
      Aout[(size_t)i * 64 + lane] = m;  // h for the head
    }
    if constexpr (DO_GMAX) gm = fmaxf(gm, m);
  }
  if constexpr (DO_GMAX) atomicMax(g + lane, __float_as_int(gm));
}

// Head: out = x + relu(h @ Wa_top + (g @ Wa_bot + ba)) @ Wb + bb
// lane c owns hidden channels c and c+64.
__global__ void k_final(const float* __restrict__ h, const float* __restrict__ g,
                        const float* __restrict__ Wa, const float* __restrict__ ba,
                        const float* __restrict__ Wb, const float* __restrict__ bb,
                        const float* __restrict__ x, float* __restrict__ out) {
  const int lane = threadIdx.x & 63;
  const int nwaves = (gridDim.x * blockDim.x) >> 6;
  const int wid0 = (blockIdx.x * blockDim.x + threadIdx.x) >> 6;
  float wa0[64], wa1[64];
#pragma unroll
  for (int k = 0; k < 64; ++k) {
    wa0[k] = Wa[k * 128 + lane];
    wa1[k] = Wa[k * 128 + 64 + lane];
  }
  float gt0 = ba[lane], gt1 = ba[64 + lane];
#pragma unroll
  for (int k = 0; k < 64; ++k) {
    const float gk = g[k];
    gt0 = fmaf(gk, Wa[(64 + k) * 128 + lane], gt0);
    gt1 = fmaf(gk, Wa[(64 + k) * 128 + 64 + lane], gt1);
  }
  float wb0[3], wb1[3];
#pragma unroll
  for (int j = 0; j < 3; ++j) {
    wb0[j] = Wb[lane * 3 + j];
    wb1[j] = Wb[(64 + lane) * 3 + j];
  }
  const float bb0 = bb[0], bb1 = bb[1], bb2 = bb[2];
  for (int i0 = wid0; i0 < N_NODES; i0 += nwaves) {
    const int i = __builtin_amdgcn_readfirstlane(i0);
    const float hv = h[(size_t)i * 64 + lane];
    float acc0 = gt0, acc1 = gt1;
#pragma unroll
    for (int k = 0; k < 64; ++k) {
      const float hk = bcast(hv, k);
      acc0 = fmaf(hk, wa0[k], acc0);
      acc1 = fmaf(hk, wa1[k], acc1);
    }
    acc0 = fmaxf(acc0, 0.f);
    acc1 = fmaxf(acc1, 0.f);
    float t0 = fmaf(acc0, wb0[0], acc1 * wb1[0]);
    float t1 = fmaf(acc0, wb0[1], acc1 * wb1[1]);
    float t2 = fmaf(acc0, wb0[2], acc1 * wb1[2]);
#pragma unroll
    for (int off = 32; off > 0; off >>= 1) {
      t0 += __shfl_xor(t0, off);
      t1 += __shfl_xor(t1, off);
      t2 += __shfl_xor(t2, off);
    }
    if (lane == 0) {
      out[3 * i]     = x[3 * i]     + t0 + bb0;
      out[3 * i + 1] = x[3 * i + 1] + t1 + bb1;
      out[3 * i + 2] = x[3 * i + 2] + t2 + bb2;
    }
  }
}

extern "C" void kernel_launch(void* const* d_in, const int* in_sizes, int n_in,
                              void* d_out, int out_size, void* d_ws, size_t ws_size,
                              hipStream_t stream) {
  const float* x  = (const float*)d_in[0];
  const int*   ei = (const int*)d_in[1];
  const float* W1 = (const float*)d_in[2];
  const float* b1 = (const float*)d_in[3];
  const float* W2 = (const float*)d_in[4];
  const float* b2 = (const float*)d_in[5];
  const float* W3 = (const float*)d_in[6];
  const float* b3 = (const float*)d_in[7];
  const float* W4 = (const float*)d_in[8];
  const float* b4 = (const float*)d_in[9];
  const float* W5 = (const float*)d_in[10];
  const float* b5 = (const float*)d_in[11];
  const float* Wa = (const float*)d_in[12];
  const float* ba = (const float*)d_in[13];
  const float* Wb = (const float*)d_in[14];
  const float* bb = (const float*)d_in[15];
  float* out = (float*)d_out;

  // workspace layout (floats): src[1.6M as int] | A0 | B0 | A1 | B1 | g[64]
  float* ws = (float*)d_ws;
  int*   srcbuf = (int*)ws;
  float* A0 = ws + 1600000;
  float* B0 = A0 + 6400000;
  float* A1 = B0 + 6400000;
  float* B1 = A1 + 6400000;
  int*   g  = (int*)(B1 + 6400000);

  k_zero_g<<<1, 64, 0, stream>>>(g);
  k_normsrc<<<NBLK, TPB, 0, stream>>>(ei, srcbuf);
  k_layer1<<<NBLK, TPB, 0, stream>>>(x, W1, b1, A0, B0);
  k_layer<true, false><<<NBLK, TPB, 0, stream>>>(srcbuf, A0, B0, W2, b2, A1, B1, nullptr);
  k_layer<true, false><<<NBLK, TPB, 0, stream>>>(srcbuf, A1, B1, W3, b3, A0, B0, nullptr);
  k_layer<true, false><<<NBLK, TPB, 0, stream>>>(srcbuf, A0, B0, W4, b4, A1, B1, nullptr);
  k_layer<true, false><<<NBLK, TPB, 0, stream>>>(srcbuf, A1, B1, W5, b5, A0, B0, nullptr);
  k_layer<false, true><<<NBLK, TPB, 0, stream>>>(srcbuf, A0, B0, nullptr, nullptr, A1, nullptr, g);
  k_final<<<NBLK, TPB, 0, stream>>>(A1, (const float*)g, Wa, ba, Wb, bb, x, out);
}

// Round 2
// 644.210 us; speedup vs baseline: 2.3421x; 2.3421x over previous
//
#include <hip/hip_runtime.h>
#include <math.h>

#define N_NODES 100000
#define K_NBRS 16
#define N_EDGES (N_NODES * K_NBRS)
#define TPB 256
#define NBLK 2048

// broadcast lane k's value of v to all lanes (k compile-time after unroll)
__device__ __forceinline__ float bcast(float v, int k) {
  return __int_as_float(__builtin_amdgcn_readlane(__float_as_int(v), k));
}

__global__ void k_zero_g(int* g) {
  if (threadIdx.x < 64) g[threadIdx.x] = 0;
}

// Normalize edge_index row 0 (src) to int32, handling either int32 or int64
// on-device (JAX x64 ambiguity). int64 little-endian: value e at words [2e,2e+1].
__global__ void k_normsrc(const int* __restrict__ ei, int* __restrict__ srcout) {
  const bool is64 = (ei[1] == 0) && (ei[3] == 0) && (ei[5] == 0) && (ei[7] == 0);
  const int tid = blockIdx.x * blockDim.x + threadIdx.x;
  const int stride = gridDim.x * blockDim.x;
  for (int e = tid; e < N_EDGES; e += stride)
    srcout[e] = is64 ? ei[2 * e] : ei[e];
}

// Layer 1: A = x @ (W1_top - W1_bot) + b1 ; B = x @ W1_bot  (C_in = 3)
__global__ void k_layer1(const float* __restrict__ x, const float* __restrict__ W1,
                         const float* __restrict__ b1,
                         float* __restrict__ A, float* __restrict__ B) {
  const int lane = threadIdx.x & 63;
  const int nwaves = (gridDim.x * blockDim.x) >> 6;
  const int wid0 = (blockIdx.x * blockDim.x + threadIdx.x) >> 6;
  float w[6];
#pragma unroll
  for (int k = 0; k < 6; ++k) w[k] = W1[k * 64 + lane];
  const float bias = b1[lane];
  for (int i0 = wid0; i0 < N_NODES; i0 += nwaves) {
    const int i = __builtin_amdgcn_readfirstlane(i0);
    const float x0 = x[3 * i], x1 = x[3 * i + 1], x2 = x[3 * i + 2];
    const float b = fmaf(x0, w[3], fmaf(x1, w[4], x2 * w[5]));
    const float a = bias + fmaf(x0, w[0] - w[3],
                          fmaf(x1, w[1] - w[4], x2 * (w[2] - w[5])));
    A[(size_t)i * 64 + lane] = a;
    B[(size_t)i * 64 + lane] = b;
  }
}

// Aggregation h[i] = max_{e<16} relu(A[i] + B[src[i*16+e]]), fused with the
// NEXT layer's node-GEMM: Aout = h @ (Wn_top - Wn_bot) + bn ; Bout = h @ Wn_bot.
// Last layer instead writes h and accumulates the global max into g.
// __launch_bounds__(256,2): cap 256 VGPR/thread so the 128-float weight
// arrays registerize (round-1 spill: VGPR=64, 383MB scratch FETCH in k_final).
template <bool DO_GEMM, bool DO_GMAX>
__global__ __launch_bounds__(TPB, 2)
void k_layer(const int* __restrict__ src,
             const float* __restrict__ Ain, const float* __restrict__ Bin,
             const float* __restrict__ Wn, const float* __restrict__ bn,
             float* __restrict__ Aout, float* __restrict__ Bout,
             int* __restrict__ g) {
  const int lane = threadIdx.x & 63;
  const int nwaves = (gridDim.x * blockDim.x) >> 6;
  const int wid0 = (blockIdx.x * blockDim.x + threadIdx.x) >> 6;
  float wA[64], wB[64];
  float bias = 0.f;
  if constexpr (DO_GEMM) {
#pragma unroll
    for (int k = 0; k < 64; ++k) {
      const float wt = Wn[k * 64 + lane];
      const float wb = Wn[(64 + k) * 64 + lane];
      wA[k] = wt - wb;
      wB[k] = wb;
    }
    bias = bn[lane];
  }
  float gm = 0.f;
  for (int i0 = wid0; i0 < N_NODES; i0 += nwaves) {
    const int i = __builtin_amdgcn_readfirstlane(i0);
    const float a = Ain[(size_t)i * 64 + lane];
    const int* sp = src + i * K_NBRS;
    float m = 0.f;  // relu output >= 0 and every node has exactly 16 edges
#pragma unroll
    for (int e = 0; e < K_NBRS; ++e) {
      const int j = sp[e];
      const float bv = Bin[(size_t)j * 64 + lane];
      m = fmaxf(m, fmaxf(a + bv, 0.f));
    }
    if constexpr (DO_GEMM) {
      float acc_a = bias, acc_b = 0.f;
#pragma unroll
      for (int k = 0; k < 64; ++k) {
        const float hk = bcast(m, k);
        acc_a = fmaf(hk, wA[k], acc_a);
        acc_b = fmaf(hk, wB[k], acc_b);
      }
      Aout[(size_t)i * 64 + lane] = acc_a;
      Bout[(size_t)i * 64 + lane] = acc_b;
    } else {
      Aout[(size_t)i * 64 + lane] = m;  // h for the head
    }
    if constexpr (DO_GMAX) gm = fmaxf(gm, m);
  }
  if constexpr (DO_GMAX) atomicMax(g + lane, __float_as_int(gm));
}

// Head: out = x + relu(h @ Wa_top + (g @ Wa_bot + ba)) @ Wb + bb
// lane c owns hidden channels c and c+64.
__global__ __launch_bounds__(TPB, 2)
void k_final(const float* __restrict__ h, const float* __restrict__ g,
             const float* __restrict__ Wa, const float* __restrict__ ba,
             const float* __restrict__ Wb, const float* __restrict__ bb,
             const float* __restrict__ x, float* __restrict__ out) {
  const int lane = threadIdx.x & 63;
  const int nwaves = (gridDim.x * blockDim.x) >> 6;
  const int wid0 = (blockIdx.x * blockDim.x + threadIdx.x) >> 6;
  float wa0[64], wa1[64];
#pragma unroll
  for (int k = 0; k < 64; ++k) {
    wa0[k] = Wa[k * 128 + lane];
    wa1[k] = Wa[k * 128 + 64 + lane];
  }
  float gt0 = ba[lane], gt1 = ba[64 + lane];
#pragma unroll
  for (int k = 0; k < 64; ++k) {
    const float gk = g[k];
    gt0 = fmaf(gk, Wa[(64 + k) * 128 + lane], gt0);
    gt1 = fmaf(gk, Wa[(64 + k) * 128 + 64 + lane], gt1);
  }
  float wb0[3], wb1[3];
#pragma unroll
  for (int j = 0; j < 3; ++j) {
    wb0[j] = Wb[lane * 3 + j];
    wb1[j] = Wb[(64 + lane) * 3 + j];
  }
  const float bb0 = bb[0], bb1 = bb[1], bb2 = bb[2];
  for (int i0 = wid0; i0 < N_NODES; i0 += nwaves) {
    const int i = __builtin_amdgcn_readfirstlane(i0);
    const float hv = h[(size_t)i * 64 + lane];
    float acc0 = gt0, acc1 = gt1;
#pragma unroll
    for (int k = 0; k < 64; ++k) {
      const float hk = bcast(hv, k);
      acc0 = fmaf(hk, wa0[k], acc0);
      acc1 = fmaf(hk, wa1[k], acc1);
    }
    acc0 = fmaxf(acc0, 0.f);
    acc1 = fmaxf(acc1, 0.f);
    float t0 = fmaf(acc0, wb0[0], acc1 * wb1[0]);
    float t1 = fmaf(acc0, wb0[1], acc1 * wb1[1]);
    float t2 = fmaf(acc0, wb0[2], acc1 * wb1[2]);
#pragma unroll
    for (int off = 32; off > 0; off >>= 1) {
      t0 += __shfl_xor(t0, off);
      t1 += __shfl_xor(t1, off);
      t2 += __shfl_xor(t2, off);
    }
    if (lane == 0) {
      out[3 * i]     = x[3 * i]     + t0 + bb0;
      out[3 * i + 1] = x[3 * i + 1] + t1 + bb1;
      out[3 * i + 2] = x[3 * i + 2] + t2 + bb2;
    }
  }
}

extern "C" void kernel_launch(void* const* d_in, const int* in_sizes, int n_in,
                              void* d_out, int out_size, void* d_ws, size_t ws_size,
                              hipStream_t stream) {
  const float* x  = (const float*)d_in[0];
  const int*   ei = (const int*)d_in[1];
  const float* W1 = (const float*)d_in[2];
  const float* b1 = (const float*)d_in[3];
  const float* W2 = (const float*)d_in[4];
  const float* b2 = (const float*)d_in[5];
  const float* W3 = (const float*)d_in[6];
  const float* b3 = (const float*)d_in[7];
  const float* W4 = (const float*)d_in[8];
  const float* b4 = (const float*)d_in[9];
  const float* W5 = (const float*)d_in[10];
  const float* b5 = (const float*)d_in[11];
  const float* Wa = (const float*)d_in[12];
  const float* ba = (const float*)d_in[13];
  const float* Wb = (const float*)d_in[14];
  const float* bb = (const float*)d_in[15];
  float* out = (float*)d_out;

  // workspace layout (floats): src[1.6M as int] | A0 | B0 | A1 | B1 | g[64]
  float* ws = (float*)d_ws;
  int*   srcbuf = (int*)ws;
  float* A0 = ws + 1600000;
  float* B0 = A0 + 6400000;
  float* A1 = B0 + 6400000;
  float* B1 = A1 + 6400000;
  int*   g  = (int*)(B1 + 6400000);

  k_zero_g<<<1, 64, 0, stream>>>(g);
  k_normsrc<<<NBLK, TPB, 0, stream>>>(ei, srcbuf);
  k_layer1<<<NBLK, TPB, 0, stream>>>(x, W1, b1, A0, B0);
  k_layer<true, false><<<NBLK, TPB, 0, stream>>>(srcbuf, A0, B0, W2, b2, A1, B1, nullptr);
  k_layer<true, false><<<NBLK, TPB, 0, stream>>>(srcbuf, A1, B1, W3, b3, A0, B0, nullptr);
  k_layer<true, false><<<NBLK, TPB, 0, stream>>>(srcbuf, A0, B0, W4, b4, A1, B1, nullptr);
  k_layer<true, false><<<NBLK, TPB, 0, stream>>>(srcbuf, A1, B1, W5, b5, A0, B0, nullptr);
  k_layer<false, true><<<NBLK, TPB, 0, stream>>>(srcbuf, A0, B0, nullptr, nullptr, A1, nullptr, g);
  k_final<<<NBLK, TPB, 0, stream>>>(A1, (const float*)g, Wa, ba, Wb, bb, x, out);
}

// Round 3
// 503.598 us; speedup vs baseline: 2.9961x; 1.2792x over previous
//
#include <hip/hip_runtime.h>
#include <hip/hip_bf16.h>
#include <math.h>

#define N_NODES 100000
#define K_NBRS 16
#define N_EDGES (N_NODES * K_NBRS)
#define TPB 256
#define NBLK 2048

typedef __hip_bfloat16 bf16;

// broadcast lane k's value of v to all lanes (k compile-time after unroll)
__device__ __forceinline__ float bcast(float v, int k) {
  return __int_as_float(__builtin_amdgcn_readlane(__float_as_int(v), k));
}

// Normalize edge_index row 0 (src) to int32, handling either int32 or int64
// on-device (JAX x64 ambiguity). int64 little-endian: value e at words [2e,2e+1].
__global__ void k_normsrc(const int* __restrict__ ei, int* __restrict__ srcout) {
  const bool is64 = (ei[1] == 0) && (ei[3] == 0) && (ei[5] == 0) && (ei[7] == 0);
  const int tid = blockIdx.x * blockDim.x + threadIdx.x;
  const int stride = gridDim.x * blockDim.x;
  for (int e = tid; e < N_EDGES; e += stride)
    srcout[e] = is64 ? ei[2 * e] : ei[e];
}

// Layer 1: A = x @ (W1_top - W1_bot) + b1 ; B = x @ W1_bot  (C_in = 3)
// B stored bf16 (gathered table); A stays fp32 (sequential read).
__global__ void k_layer1(const float* __restrict__ x, const float* __restrict__ W1,
                         const float* __restrict__ b1,
                         float* __restrict__ A, bf16* __restrict__ B) {
  const int lane = threadIdx.x & 63;
  const int nwaves = (gridDim.x * blockDim.x) >> 6;
  const int wid0 = (blockIdx.x * blockDim.x + threadIdx.x) >> 6;
  float w[6];
#pragma unroll
  for (int k = 0; k < 6; ++k) w[k] = W1[k * 64 + lane];
  const float bias = b1[lane];
  for (int i0 = wid0; i0 < N_NODES; i0 += nwaves) {
    const int i = __builtin_amdgcn_readfirstlane(i0);
    const float x0 = x[3 * i], x1 = x[3 * i + 1], x2 = x[3 * i + 2];
    const float b = fmaf(x0, w[3], fmaf(x1, w[4], x2 * w[5]));
    const float a = bias + fmaf(x0, w[0] - w[3],
                          fmaf(x1, w[1] - w[4], x2 * (w[2] - w[5])));
    A[(size_t)i * 64 + lane] = a;
    B[(size_t)i * 64 + lane] = __float2bfloat16(b);
  }
}

// Aggregation h[i] = max_{e<16} relu(A[i] + B[src[i*16+e]]), fused with the
// NEXT layer's node-GEMM: Aout = h @ (Wn_top - Wn_bot) + bn ; Bout = h @ Wn_bot.
// Last layer (DO_GEMM=false) writes h and per-block global-max partials
// (no atomics: 524k same-address atomicMax ops cost ~170us in round 2).
template <bool DO_GEMM, bool DO_GMAX>
__global__ __launch_bounds__(TPB, 2)
void k_layer(const int* __restrict__ src,
             const float* __restrict__ Ain, const bf16* __restrict__ Bin,
             const float* __restrict__ Wn, const float* __restrict__ bn,
             float* __restrict__ Aout, bf16* __restrict__ Bout,
             float* __restrict__ P) {
  const int lane = threadIdx.x & 63;
  const int nwaves = (gridDim.x * blockDim.x) >> 6;
  const int wid0 = (blockIdx.x * blockDim.x + threadIdx.x) >> 6;
  float wA[64], wB[64];
  float bias = 0.f;
  if constexpr (DO_GEMM) {
#pragma unroll
    for (int k = 0; k < 64; ++k) {
      const float wt = Wn[k * 64 + lane];
      const float wb = Wn[(64 + k) * 64 + lane];
      wA[k] = wt - wb;
      wB[k] = wb;
    }
    bias = bn[lane];
  }
  float gm = 0.f;
  for (int i0 = wid0; i0 < N_NODES; i0 += nwaves) {
    const int i = __builtin_amdgcn_readfirstlane(i0);
    const float a = Ain[(size_t)i * 64 + lane];
    const int* sp = src + i * K_NBRS;
    float m = 0.f;  // relu output >= 0 and every node has exactly 16 edges
#pragma unroll
    for (int e = 0; e < K_NBRS; ++e) {
      const int j = sp[e];
      const float bv = __bfloat162float(Bin[(size_t)j * 64 + lane]);
      m = fmaxf(m, fmaxf(a + bv, 0.f));
    }
    if constexpr (DO_GEMM) {
      float acc_a = bias, acc_b = 0.f;
#pragma unroll
      for (int k = 0; k < 64; ++k) {
        const float hk = bcast(m, k);
        acc_a = fmaf(hk, wA[k], acc_a);
        acc_b = fmaf(hk, wB[k], acc_b);
      }
      Aout[(size_t)i * 64 + lane] = acc_a;
      Bout[(size_t)i * 64 + lane] = __float2bfloat16(acc_b);
    } else {
      Aout[(size_t)i * 64 + lane] = m;  // h for the head
    }
    if constexpr (DO_GMAX) gm = fmaxf(gm, m);
  }
  if constexpr (DO_GMAX) {
    __shared__ float red[TPB];
    red[threadIdx.x] = gm;
    __syncthreads();
    if (threadIdx.x < 64) {
      const float mm = fmaxf(fmaxf(red[threadIdx.x], red[threadIdx.x + 64]),
                             fmaxf(red[threadIdx.x + 128], red[threadIdx.x + 192]));
      P[(size_t)blockIdx.x * 64 + threadIdx.x] = mm;
    }
  }
}

// Tree-reduce the 2048 per-block partials to g[64]. One block, 16 waves.
__global__ void k_gred(const float* __restrict__ P, float* __restrict__ g) {
  __shared__ float red[16][64];
  const int lane = threadIdx.x & 63;
  const int w = threadIdx.x >> 6;
  float m = 0.f;
  for (int r = w; r < NBLK; r += 16)
    m = fmaxf(m, P[(size_t)r * 64 + lane]);
  red[w][lane] = m;
  __syncthreads();
  if (threadIdx.x < 64) {
    float mm = 0.f;
#pragma unroll
    for (int k = 0; k < 16; ++k) mm = fmaxf(mm, red[k][lane]);
    g[lane] = mm;
  }
}

// Head: out = x + relu(h @ Wa_top + (g @ Wa_bot + ba)) @ Wb + bb
// lane c owns hidden channels c and c+64.
__global__ __launch_bounds__(TPB, 2)
void k_final(const float* __restrict__ h, const float* __restrict__ g,
             const float* __restrict__ Wa, const float* __restrict__ ba,
             const float* __restrict__ Wb, const float* __restrict__ bb,
             const float* __restrict__ x, float* __restrict__ out) {
  const int lane = threadIdx.x & 63;
  const int nwaves = (gridDim.x * blockDim.x) >> 6;
  const int wid0 = (blockIdx.x * blockDim.x + threadIdx.x) >> 6;
  float wa0[64], wa1[64];
#pragma unroll
  for (int k = 0; k < 64; ++k) {
    wa0[k] = Wa[k * 128 + lane];
    wa1[k] = Wa[k * 128 + 64 + lane];
  }
  float gt0 = ba[lane], gt1 = ba[64 + lane];
#pragma unroll
  for (int k = 0; k < 64; ++k) {
    const float gk = g[k];
    gt0 = fmaf(gk, Wa[(64 + k) * 128 + lane], gt0);
    gt1 = fmaf(gk, Wa[(64 + k) * 128 + 64 + lane], gt1);
  }
  float wb0[3], wb1[3];
#pragma unroll
  for (int j = 0; j < 3; ++j) {
    wb0[j] = Wb[lane * 3 + j];
    wb1[j] = Wb[(64 + lane) * 3 + j];
  }
  const float bb0 = bb[0], bb1 = bb[1], bb2 = bb[2];
  for (int i0 = wid0; i0 < N_NODES; i0 += nwaves) {
    const int i = __builtin_amdgcn_readfirstlane(i0);
    const float hv = h[(size_t)i * 64 + lane];
    float acc0 = gt0, acc1 = gt1;
#pragma unroll
    for (int k = 0; k < 64; ++k) {
      const float hk = bcast(hv, k);
      acc0 = fmaf(hk, wa0[k], acc0);
      acc1 = fmaf(hk, wa1[k], acc1);
    }
    acc0 = fmaxf(acc0, 0.f);
    acc1 = fmaxf(acc1, 0.f);
    float t0 = fmaf(acc0, wb0[0], acc1 * wb1[0]);
    float t1 = fmaf(acc0, wb0[1], acc1 * wb1[1]);
    float t2 = fmaf(acc0, wb0[2], acc1 * wb1[2]);
#pragma unroll
    for (int off = 32; off > 0; off >>= 1) {
      t0 += __shfl_xor(t0, off);
      t1 += __shfl_xor(t1, off);
      t2 += __shfl_xor(t2, off);
    }
    if (lane == 0) {
      out[3 * i]     = x[3 * i]     + t0 + bb0;
      out[3 * i + 1] = x[3 * i + 1] + t1 + bb1;
      out[3 * i + 2] = x[3 * i + 2] + t2 + bb2;
    }
  }
}

extern "C" void kernel_launch(void* const* d_in, const int* in_sizes, int n_in,
                              void* d_out, int out_size, void* d_ws, size_t ws_size,
                              hipStream_t stream) {
  const float* x  = (const float*)d_in[0];
  const int*   ei = (const int*)d_in[1];
  const float* W1 = (const float*)d_in[2];
  const float* b1 = (const float*)d_in[3];
  const float* W2 = (const float*)d_in[4];
  const float* b2 = (const float*)d_in[5];
  const float* W3 = (const float*)d_in[6];
  const float* b3 = (const float*)d_in[7];
  const float* W4 = (const float*)d_in[8];
  const float* b4 = (const float*)d_in[9];
  const float* W5 = (const float*)d_in[10];
  const float* b5 = (const float*)d_in[11];
  const float* Wa = (const float*)d_in[12];
  const float* ba = (const float*)d_in[13];
  const float* Wb = (const float*)d_in[14];
  const float* bb = (const float*)d_in[15];
  float* out = (float*)d_out;

  // workspace layout (float words):
  // src[1.6M] | A0[6.4M] | A1[6.4M] | B0[3.2M: bf16 x 6.4M] | B1[3.2M] |
  // P[2048*64] | g[64]
  float* ws = (float*)d_ws;
  int*   srcbuf = (int*)ws;
  float* A0 = ws + 1600000;
  float* A1 = A0 + 6400000;
  bf16*  B0 = (bf16*)(A1 + 6400000);
  bf16*  B1 = (bf16*)((float*)B0 + 3200000);
  float* P  = (float*)B1 + 3200000;
  float* g  = P + (size_t)NBLK * 64;

  k_normsrc<<<NBLK, TPB, 0, stream>>>(ei, srcbuf);
  k_layer1<<<NBLK, TPB, 0, stream>>>(x, W1, b1, A0, B0);
  k_layer<true, false><<<NBLK, TPB, 0, stream>>>(srcbuf, A0, B0, W2, b2, A1, B1, nullptr);
  k_layer<true, false><<<NBLK, TPB, 0, stream>>>(srcbuf, A1, B1, W3, b3, A0, B0, nullptr);
  k_layer<true, false><<<NBLK, TPB, 0, stream>>>(srcbuf, A0, B0, W4, b4, A1, B1, nullptr);
  k_layer<true, false><<<NBLK, TPB, 0, stream>>>(srcbuf, A1, B1, W5, b5, A0, B0, nullptr);
  k_layer<false, true><<<NBLK, TPB, 0, stream>>>(srcbuf, A0, B0, nullptr, nullptr, A1, nullptr, P);
  k_gred<<<1, 1024, 0, stream>>>(P, g);
  k_final<<<NBLK, TPB, 0, stream>>>(A1, g, Wa, ba, Wb, bb, x, out);
}

// Round 4
// 419.774 us; speedup vs baseline: 3.5944x; 1.1997x over previous
//
#include <hip/hip_runtime.h>
#include <math.h>

#define N_NODES 100000
#define K_NBRS 16
#define N_EDGES (N_NODES * K_NBRS)
#define TPB 256
#define NBLK 2048

typedef __attribute__((ext_vector_type(8))) short short8;   // bf16x8 MFMA frag
typedef __attribute__((ext_vector_type(8))) float float8;
typedef __attribute__((ext_vector_type(4))) float float4_;  // MFMA C/D frag

// RNE float->bf16 (bits) and back; matches hardware/JAX rounding for finite vals
__device__ __forceinline__ unsigned short f2bf(float f) {
  unsigned int u = __float_as_uint(f);
  u += 0x7fffu + ((u >> 16) & 1u);
  return (unsigned short)(u >> 16);
}
__device__ __forceinline__ float bf2f(unsigned short b) {
  return __uint_as_float(((unsigned int)b) << 16);
}

// Normalize edge_index row 0 (src) to int32 (handles int32 or int64 input).
__global__ void k_normsrc(const int* __restrict__ ei, int* __restrict__ srcout) {
  const bool is64 = (ei[1] == 0) && (ei[3] == 0) && (ei[5] == 0) && (ei[7] == 0);
  const int tid = blockIdx.x * blockDim.x + threadIdx.x;
  const int stride = gridDim.x * blockDim.x;
  for (int e = tid; e < N_EDGES; e += stride)
    srcout[e] = is64 ? ei[2 * e] : ei[e];
}

// Layer 1: A = x @ (W1_top - W1_bot) + b1 (fp32) ; B = x @ W1_bot (bf16 table)
__global__ void k_layer1(const float* __restrict__ x, const float* __restrict__ W1,
                         const float* __restrict__ b1,
                         float* __restrict__ A, unsigned short* __restrict__ B) {
  const int lane = threadIdx.x & 63;
  const int nwaves = (gridDim.x * blockDim.x) >> 6;
  const int wid0 = (blockIdx.x * blockDim.x + threadIdx.x) >> 6;
  float w[6];
#pragma unroll
  for (int k = 0; k < 6; ++k) w[k] = W1[k * 64 + lane];
  const float bias = b1[lane];
  for (int i0 = wid0; i0 < N_NODES; i0 += nwaves) {
    const int i = __builtin_amdgcn_readfirstlane(i0);
    const float x0 = x[3 * i], x1 = x[3 * i + 1], x2 = x[3 * i + 2];
    const float b = fmaf(x0, w[3], fmaf(x1, w[4], x2 * w[5]));
    const float a = bias + fmaf(x0, w[0] - w[3],
                          fmaf(x1, w[1] - w[4], x2 * (w[2] - w[5])));
    A[(size_t)i * 64 + lane] = a;
    B[(size_t)i * 64 + lane] = f2bf(b);
  }
}

// Gather + max aggregation only: h[i] = max_e relu(A[i] + B[src[i*16+e]]).
// Tiny VGPR footprint -> full occupancy; 2 nodes/iter -> 32 gathers in flight.
template <bool DO_GMAX>
__global__ void k_aggr(const int* __restrict__ src,
                       const float* __restrict__ Ain,
                       const unsigned short* __restrict__ Bin,
                       float* __restrict__ hout, float* __restrict__ P) {
  const int lane = threadIdx.x & 63;
  const int nw = (gridDim.x * blockDim.x) >> 6;
  const int w0 = (blockIdx.x * blockDim.x + threadIdx.x) >> 6;
  float gm = 0.f;
  for (int p = w0; p * 2 < N_NODES; p += nw) {
    const int i = __builtin_amdgcn_readfirstlane(p * 2);
    const int* sp = src + (size_t)i * K_NBRS;   // 32 indices (2 nodes), uniform
    unsigned short gv[32];
#pragma unroll
    for (int e = 0; e < 32; ++e)
      gv[e] = Bin[(size_t)sp[e] * 64 + lane];
    const float a0 = Ain[(size_t)i * 64 + lane];
    const float a1 = Ain[(size_t)(i + 1) * 64 + lane];
    float m0 = 0.f, m1 = 0.f;  // relu folded into init (outputs >= 0)
#pragma unroll
    for (int e = 0; e < 16; ++e) m0 = fmaxf(m0, a0 + bf2f(gv[e]));
#pragma unroll
    for (int e = 0; e < 16; ++e) m1 = fmaxf(m1, a1 + bf2f(gv[16 + e]));
    hout[(size_t)i * 64 + lane] = m0;
    hout[(size_t)(i + 1) * 64 + lane] = m1;
    if constexpr (DO_GMAX) gm = fmaxf(gm, fmaxf(m0, m1));
  }
  if constexpr (DO_GMAX) {
    __shared__ float red[TPB];
    red[threadIdx.x] = gm;
    __syncthreads();
    if (threadIdx.x < 64) {
      P[(size_t)blockIdx.x * 64 + threadIdx.x] =
          fmaxf(fmaxf(red[threadIdx.x], red[threadIdx.x + 64]),
                fmaxf(red[threadIdx.x + 128], red[threadIdx.x + 192]));
    }
  }
}

// MFMA node-GEMM: [Aout|Bout] = h @ [Wtop-Wbot | Wbot] (+bias on A).
// Split-precision: h=hi+lo, W=hi+lo (bf16 pairs), 3 MFMAs -> ~fp32 accuracy.
// Frags (16x16x32 bf16): A row=lane&15, k=(lane>>4)*8+e; B col=lane&15, same k;
// C/D col=lane&15, row=(lane>>4)*4+reg (m89-verified).
__global__ __launch_bounds__(TPB, 2)
void k_gemm(const float* __restrict__ h, const float* __restrict__ W,
            const float* __restrict__ bn,
            float* __restrict__ Aout, unsigned short* __restrict__ Bout) {
  __shared__ unsigned short lwhi[128 * 72];  // W'^T [j][k], stride 72 (bank-safe)
  __shared__ unsigned short lwlo[128 * 72];
  for (int idx = threadIdx.x; idx < 8192; idx += TPB) {
    const int k = idx >> 7, j = idx & 127;
    const float v = (j < 64) ? (W[k * 64 + j] - W[(64 + k) * 64 + j])
                             : W[(64 + k) * 64 + (j - 64)];
    const unsigned short hi = f2bf(v);
    lwhi[j * 72 + k] = hi;
    lwlo[j * 72 + k] = f2bf(v - bf2f(hi));
  }
  __syncthreads();
  const int lane = threadIdx.x & 63;
  const int wav = threadIdx.x >> 6;
  const int l15 = lane & 15, lg = lane >> 4;
  short8 bhi[8][2], blo[8][2];
#pragma unroll
  for (int ct = 0; ct < 8; ++ct)
#pragma unroll
    for (int kk = 0; kk < 2; ++kk) {
      const int off = (ct * 16 + l15) * 72 + kk * 32 + lg * 8;
      bhi[ct][kk] = *(const short8*)&lwhi[off];
      blo[ct][kk] = *(const short8*)&lwlo[off];
    }
  float bv[4];
#pragma unroll
  for (int ct = 0; ct < 4; ++ct) bv[ct] = bn[ct * 16 + l15];
  const int NT = (N_NODES + 63) / 64;
  for (int t = blockIdx.x; t < NT; t += gridDim.x) {
    const int nb = t * 64 + wav * 16;
    const int row = min(nb + l15, N_NODES - 1);
    const float* hr = h + (size_t)row * 64;
    float4_ acc[8];
#pragma unroll
    for (int ct = 0; ct < 8; ++ct) acc[ct] = (float4_)(0.f);
#pragma unroll
    for (int kk = 0; kk < 2; ++kk) {
      const float8 hv = *(const float8*)(hr + kk * 32 + lg * 8);
      short8 ahi, alo;
#pragma unroll
      for (int e = 0; e < 8; ++e) {
        const unsigned short hb = f2bf(hv[e]);
        ahi[e] = (short)hb;
        alo[e] = (short)f2bf(hv[e] - bf2f(hb));
      }
#pragma unroll
      for (int ct = 0; ct < 8; ++ct) {
        acc[ct] = __builtin_amdgcn_mfma_f32_16x16x32_bf16(ahi, bhi[ct][kk], acc[ct], 0, 0, 0);
        acc[ct] = __builtin_amdgcn_mfma_f32_16x16x32_bf16(alo, bhi[ct][kk], acc[ct], 0, 0, 0);
        acc[ct] = __builtin_amdgcn_mfma_f32_16x16x32_bf16(ahi, blo[ct][kk], acc[ct], 0, 0, 0);
      }
    }
#pragma unroll
    for (int ct = 0; ct < 8; ++ct)
#pragma unroll
      for (int r = 0; r < 4; ++r) {
        const int node = nb + lg * 4 + r;
        if (node < N_NODES) {
          if (ct < 4)
            Aout[(size_t)node * 64 + ct * 16 + l15] = acc[ct][r] + bv[ct];
          else
            Bout[(size_t)node * 64 + (ct - 4) * 16 + l15] = f2bf(acc[ct][r]);
        }
      }
  }
}

// Tree-reduce 2048 per-block partials to g[64].
__global__ void k_gred(const float* __restrict__ P, float* __restrict__ g) {
  __shared__ float red[16][64];
  const int lane = threadIdx.x & 63;
  const int w = threadIdx.x >> 6;
  float m = 0.f;
  for (int r = w; r < NBLK; r += 16)
    m = fmaxf(m, P[(size_t)r * 64 + lane]);
  red[w][lane] = m;
  __syncthreads();
  if (threadIdx.x < 64) {
    float mm = 0.f;
#pragma unroll
    for (int k = 0; k < 16; ++k) mm = fmaxf(mm, red[k][lane]);
    g[lane] = mm;
  }
}

// Head: hidden = relu(h @ Wa_top + gt), gt[c] = ba[c] + sum_k g[k] Wa[64+k][c];
// out = x + hidden @ Wb + bb. GEMM1 via split MFMA, then in-register 128->3 dot.
__global__ __launch_bounds__(TPB, 2)
void k_final(const float* __restrict__ h, const float* __restrict__ g,
             const float* __restrict__ Wa, const float* __restrict__ ba,
             const float* __restrict__ Wb, const float* __restrict__ bb,
             const float* __restrict__ x, float* __restrict__ out) {
  __shared__ unsigned short lwhi[128 * 72];
  __shared__ unsigned short lwlo[128 * 72];
  __shared__ float sgt[128];
  for (int idx = threadIdx.x; idx < 8192; idx += TPB) {
    const int k = idx >> 7, j = idx & 127;
    const float v = Wa[k * 128 + j];
    const unsigned short hi = f2bf(v);
    lwhi[j * 72 + k] = hi;
    lwlo[j * 72 + k] = f2bf(v - bf2f(hi));
  }
  if (threadIdx.x < 128) {
    const int c = threadIdx.x;
    float s = ba[c];
    for (int k = 0; k < 64; ++k) s = fmaf(g[k], Wa[(64 + k) * 128 + c], s);
    sgt[c] = s;
  }
  __syncthreads();
  const int lane = threadIdx.x & 63;
  const int wav = threadIdx.x >> 6;
  const int l15 = lane & 15, lg = lane >> 4;
  short8 bhi[8][2], blo[8][2];
#pragma unroll
  for (int ct = 0; ct < 8; ++ct)
#pragma unroll
    for (int kk = 0; kk < 2; ++kk) {
      const int off = (ct * 16 + l15) * 72 + kk * 32 + lg * 8;
      bhi[ct][kk] = *(const short8*)&lwhi[off];
      blo[ct][kk] = *(const short8*)&lwlo[off];
    }
  float gtv[8];
#pragma unroll
  for (int ct = 0; ct < 8; ++ct) gtv[ct] = sgt[ct * 16 + l15];
  float wbv[8][3];
#pragma unroll
  for (int ct = 0; ct < 8; ++ct)
#pragma unroll
    for (int jj = 0; jj < 3; ++jj)
      wbv[ct][jj] = Wb[(ct * 16 + l15) * 3 + jj];
  const float bbl = (l15 == 0) ? bb[0] : (l15 == 1 ? bb[1] : bb[2]);
  const int NT = (N_NODES + 63) / 64;
  for (int t = blockIdx.x; t < NT; t += gridDim.x) {
    const int nb = t * 64 + wav * 16;
    const int row = min(nb + l15, N_NODES - 1);
    const float* hr = h + (size_t)row * 64;
    float4_ acc[8];
#pragma unroll
    for (int ct = 0; ct < 8; ++ct) acc[ct] = (float4_)(0.f);
#pragma unroll
    for (int kk = 0; kk < 2; ++kk) {
      const float8 hv = *(const float8*)(hr + kk * 32 + lg * 8);
      short8 ahi, alo;
#pragma unroll
      for (int e = 0; e < 8; ++e) {
        const unsigned short hb = f2bf(hv[e]);
        ahi[e] = (short)hb;
        alo[e] = (short)f2bf(hv[e] - bf2f(hb));
      }
#pragma unroll
      for (int ct = 0; ct < 8; ++ct) {
        acc[ct] = __builtin_amdgcn_mfma_f32_16x16x32_bf16(ahi, bhi[ct][kk], acc[ct], 0, 0, 0);
        acc[ct] = __builtin_amdgcn_mfma_f32_16x16x32_bf16(alo, bhi[ct][kk], acc[ct], 0, 0, 0);
        acc[ct] = __builtin_amdgcn_mfma_f32_16x16x32_bf16(ahi, blo[ct][kk], acc[ct], 0, 0, 0);
      }
    }
#pragma unroll
    for (int r = 0; r < 4; ++r) {
      float t0 = 0.f, t1 = 0.f, t2 = 0.f;
#pragma unroll
      for (int ct = 0; ct < 8; ++ct) {
        const float hd = fmaxf(acc[ct][r] + gtv[ct], 0.f);
        t0 = fmaf(hd, wbv[ct][0], t0);
        t1 = fmaf(hd, wbv[ct][1], t1);
        t2 = fmaf(hd, wbv[ct][2], t2);
      }
#pragma unroll
      for (int off = 1; off < 16; off <<= 1) {
        t0 += __shfl_xor(t0, off);
        t1 += __shfl_xor(t1, off);
        t2 += __shfl_xor(t2, off);
      }
      const int node = nb + lg * 4 + r;
      if (node < N_NODES && l15 < 3) {
        const float tj = (l15 == 0) ? t0 : (l15 == 1 ? t1 : t2);
        out[(size_t)node * 3 + l15] = x[(size_t)node * 3 + l15] + tj + bbl;
      }
    }
  }
}

extern "C" void kernel_launch(void* const* d_in, const int* in_sizes, int n_in,
                              void* d_out, int out_size, void* d_ws, size_t ws_size,
                              hipStream_t stream) {
  const float* x  = (const float*)d_in[0];
  const int*   ei = (const int*)d_in[1];
  const float* W1 = (const float*)d_in[2];
  const float* b1 = (const float*)d_in[3];
  const float* W2 = (const float*)d_in[4];
  const float* b2 = (const float*)d_in[5];
  const float* W3 = (const float*)d_in[6];
  const float* b3 = (const float*)d_in[7];
  const float* W4 = (const float*)d_in[8];
  const float* b4 = (const float*)d_in[9];
  const float* W5 = (const float*)d_in[10];
  const float* b5 = (const float*)d_in[11];
  const float* Wa = (const float*)d_in[12];
  const float* ba = (const float*)d_in[13];
  const float* Wb = (const float*)d_in[14];
  const float* bb = (const float*)d_in[15];
  float* out = (float*)d_out;

  // ws layout (float words): src[1.6M] | A0[6.4M] | A1[6.4M] | H[6.4M] |
  // B0[3.2M words = 6.4M bf16] | B1[3.2M] | P[2048*64] | g[64]
  float* ws = (float*)d_ws;
  int* srcbuf = (int*)ws;
  float* A0 = ws + 1600000;
  float* A1 = A0 + 6400000;
  float* H  = A1 + 6400000;
  unsigned short* B0 = (unsigned short*)(H + 6400000);
  unsigned short* B1 = B0 + 6400000;
  float* P = (float*)(B1 + 6400000);
  float* g = P + (size_t)NBLK * 64;

  k_normsrc<<<1024, TPB, 0, stream>>>(ei, srcbuf);
  k_layer1<<<NBLK, TPB, 0, stream>>>(x, W1, b1, A0, B0);
  k_aggr<false><<<NBLK, TPB, 0, stream>>>(srcbuf, A0, B0, H, nullptr);
  k_gemm<<<512, TPB, 0, stream>>>(H, W2, b2, A1, B1);
  k_aggr<false><<<NBLK, TPB, 0, stream>>>(srcbuf, A1, B1, H, nullptr);
  k_gemm<<<512, TPB, 0, stream>>>(H, W3, b3, A0, B0);
  k_aggr<false><<<NBLK, TPB, 0, stream>>>(srcbuf, A0, B0, H, nullptr);
  k_gemm<<<512, TPB, 0, stream>>>(H, W4, b4, A1, B1);
  k_aggr<false><<<NBLK, TPB, 0, stream>>>(srcbuf, A1, B1, H, nullptr);
  k_gemm<<<512, TPB, 0, stream>>>(H, W5, b5, A0, B0);
  k_aggr<true><<<NBLK, TPB, 0, stream>>>(srcbuf, A0, B0, H, P);
  k_gred<<<1, 1024, 0, stream>>>(P, g);
  k_final<<<512, TPB, 0, stream>>>(H, g, Wa, ba, Wb, bb, x, out);
}

// Round 5
// 378.508 us; speedup vs baseline: 3.9862x; 1.1090x over previous
//
#include <hip/hip_runtime.h>
#include <math.h>

#define N_NODES 100000
#define K_NBRS 16
#define N_EDGES (N_NODES * K_NBRS)
#define TPB 256
#define NBLK 2048

typedef __attribute__((ext_vector_type(8))) short short8;   // bf16x8 MFMA frag
typedef __attribute__((ext_vector_type(8))) float float8;
typedef __attribute__((ext_vector_type(4))) float float4_;  // MFMA C/D frag
typedef __attribute__((ext_vector_type(4))) int int4_;
typedef __attribute__((ext_vector_type(4))) unsigned short ushort4_;

// RNE float->bf16 (bits) and back
__device__ __forceinline__ unsigned short f2bf(float f) {
  unsigned int u = __float_as_uint(f);
  u += 0x7fffu + ((u >> 16) & 1u);
  return (unsigned short)(u >> 16);
}
__device__ __forceinline__ float bf2f(unsigned short b) {
  return __uint_as_float(((unsigned int)b) << 16);
}

// Normalize edge_index row 0 (src) to int32 (handles int32 or int64 input).
__global__ void k_normsrc(const int* __restrict__ ei, int* __restrict__ srcout) {
  const bool is64 = (ei[1] == 0) && (ei[3] == 0) && (ei[5] == 0) && (ei[7] == 0);
  const int tid = blockIdx.x * blockDim.x + threadIdx.x;
  const int stride = gridDim.x * blockDim.x;
  for (int e = tid; e < N_EDGES; e += stride)
    srcout[e] = is64 ? ei[2 * e] : ei[e];
}

// Layer 1: A = x @ (W1_top - W1_bot) + b1 (fp32) ; B = x @ W1_bot (bf16 table)
__global__ void k_layer1(const float* __restrict__ x, const float* __restrict__ W1,
                         const float* __restrict__ b1,
                         float* __restrict__ A, unsigned short* __restrict__ B) {
  const int lane = threadIdx.x & 63;
  const int nwaves = (gridDim.x * blockDim.x) >> 6;
  const int wid0 = (blockIdx.x * blockDim.x + threadIdx.x) >> 6;
  float w[6];
#pragma unroll
  for (int k = 0; k < 6; ++k) w[k] = W1[k * 64 + lane];
  const float bias = b1[lane];
  for (int i0 = wid0; i0 < N_NODES; i0 += nwaves) {
    const int i = __builtin_amdgcn_readfirstlane(i0);
    const float x0 = x[3 * i], x1 = x[3 * i + 1], x2 = x[3 * i + 2];
    const float b = fmaf(x0, w[3], fmaf(x1, w[4], x2 * w[5]));
    const float a = bias + fmaf(x0, w[0] - w[3],
                          fmaf(x1, w[1] - w[4], x2 * (w[2] - w[5])));
    A[(size_t)i * 64 + lane] = a;
    B[(size_t)i * 64 + lane] = f2bf(b);
  }
}

// Gather + max aggregation: h[i] = relu(A[i] + max_e B[src[i*16+e]]).
// Packed dwordx2 gathers: lane quarter q owns table rows 4q..4q+3 of its node,
// (lane&15) owns 4 channels -> each gather instr pulls 4 rows x 128B.
// 4 nodes/iter -> 16 gathers (8KB) in flight per wave. H written as bf16.
template <bool DO_GMAX>
__global__ void k_aggr(const int* __restrict__ src,
                       const float* __restrict__ Ain,
                       const unsigned short* __restrict__ Bin,
                       unsigned short* __restrict__ hout, float* __restrict__ P) {
  const int lane = threadIdx.x & 63;
  const int q = lane >> 4;         // quarter: rows 4q..4q+3, node i0+q epilogue
  const int c4 = (lane & 15) * 4;  // 4 channels per lane
  const int nw = (gridDim.x * blockDim.x) >> 6;
  const int w0 = (blockIdx.x * blockDim.x + threadIdx.x) >> 6;
  float4_ gmax = (float4_)(0.f);
  for (int p = w0; p * 4 < N_NODES; p += nw) {
    const int i0 = __builtin_amdgcn_readfirstlane(p * 4);
    int4_ idx[4];
#pragma unroll
    for (int n = 0; n < 4; ++n)
      idx[n] = *(const int4_*)(src + (size_t)(i0 + n) * 16 + q * 4);
    ushort4_ gv[4][4];
#pragma unroll
    for (int n = 0; n < 4; ++n)
#pragma unroll
      for (int e = 0; e < 4; ++e)
        gv[n][e] = *(const ushort4_*)(Bin + (size_t)idx[n][e] * 64 + c4);
    const float4_ av = *(const float4_*)(Ain + (size_t)(i0 + q) * 64 + c4);
    float4_ m[4];
#pragma unroll
    for (int n = 0; n < 4; ++n) {
#pragma unroll
      for (int t = 0; t < 4; ++t) {
        const float v0 = bf2f(gv[n][0][t]), v1 = bf2f(gv[n][1][t]);
        const float v2 = bf2f(gv[n][2][t]), v3 = bf2f(gv[n][3][t]);
        m[n][t] = fmaxf(fmaxf(v0, v1), fmaxf(v2, v3));
      }
#pragma unroll
      for (int t = 0; t < 4; ++t) {  // cross-quarter (rows) reduce
        float v = m[n][t];
        v = fmaxf(v, __shfl_xor(v, 16));
        v = fmaxf(v, __shfl_xor(v, 32));
        m[n][t] = v;
      }
    }
    ushort4_ hb;
#pragma unroll
    for (int t = 0; t < 4; ++t) {  // select m[q] (static chain, no scratch)
      float v = m[0][t];
      v = (q == 1) ? m[1][t] : v;
      v = (q == 2) ? m[2][t] : v;
      v = (q == 3) ? m[3][t] : v;
      const float h = fmaxf(av[t] + v, 0.f);
      hb[t] = f2bf(h);
      if constexpr (DO_GMAX) gmax[t] = fmaxf(gmax[t], h);
    }
    *(ushort4_*)(hout + (size_t)(i0 + q) * 64 + c4) = hb;
  }
  if constexpr (DO_GMAX) {
    __shared__ float red[TPB][4];
#pragma unroll
    for (int t = 0; t < 4; ++t) red[threadIdx.x][t] = gmax[t];
    __syncthreads();
    if (threadIdx.x < 64) {
      const int c = threadIdx.x, j = c >> 2, t = c & 3;
      float mm = 0.f;
#pragma unroll
      for (int w = 0; w < 4; ++w)
#pragma unroll
        for (int qq = 0; qq < 4; ++qq)
          mm = fmaxf(mm, red[w * 64 + qq * 16 + j][t]);
      P[(size_t)blockIdx.x * 64 + c] = mm;
    }
  }
}

// MFMA node-GEMM: [Aout|Bout] = h @ [Wtop-Wbot | Wbot] (+bias on A).
// h is bf16 (direct A-frag); weights split hi+lo -> 2 MFMAs per tile.
__global__ __launch_bounds__(TPB, 2)
void k_gemm(const unsigned short* __restrict__ h, const float* __restrict__ W,
            const float* __restrict__ bn,
            float* __restrict__ Aout, unsigned short* __restrict__ Bout) {
  __shared__ unsigned short lwhi[128 * 72];  // W'^T [j][k], stride 72
  __shared__ unsigned short lwlo[128 * 72];
  for (int idx = threadIdx.x; idx < 8192; idx += TPB) {
    const int k = idx >> 7, j = idx & 127;
    const float v = (j < 64) ? (W[k * 64 + j] - W[(64 + k) * 64 + j])
                             : W[(64 + k) * 64 + (j - 64)];
    const unsigned short hi = f2bf(v);
    lwhi[j * 72 + k] = hi;
    lwlo[j * 72 + k] = f2bf(v - bf2f(hi));
  }
  __syncthreads();
  const int lane = threadIdx.x & 63;
  const int wav = threadIdx.x >> 6;
  const int l15 = lane & 15, lg = lane >> 4;
  short8 bhi[8][2], blo[8][2];
#pragma unroll
  for (int ct = 0; ct < 8; ++ct)
#pragma unroll
    for (int kk = 0; kk < 2; ++kk) {
      const int off = (ct * 16 + l15) * 72 + kk * 32 + lg * 8;
      bhi[ct][kk] = *(const short8*)&lwhi[off];
      blo[ct][kk] = *(const short8*)&lwlo[off];
    }
  float bv[4];
#pragma unroll
  for (int ct = 0; ct < 4; ++ct) bv[ct] = bn[ct * 16 + l15];
  const int NT = (N_NODES + 63) / 64;
  for (int t = blockIdx.x; t < NT; t += gridDim.x) {
    const int nb = t * 64 + wav * 16;
    const int row = min(nb + l15, N_NODES - 1);
    const unsigned short* hr = h + (size_t)row * 64;
    float4_ acc[8];
#pragma unroll
    for (int ct = 0; ct < 8; ++ct) acc[ct] = (float4_)(0.f);
#pragma unroll
    for (int kk = 0; kk < 2; ++kk) {
      const short8 ahi = *(const short8*)(hr + kk * 32 + lg * 8);
#pragma unroll
      for (int ct = 0; ct < 8; ++ct) {
        acc[ct] = __builtin_amdgcn_mfma_f32_16x16x32_bf16(ahi, bhi[ct][kk], acc[ct], 0, 0, 0);
        acc[ct] = __builtin_amdgcn_mfma_f32_16x16x32_bf16(ahi, blo[ct][kk], acc[ct], 0, 0, 0);
      }
    }
#pragma unroll
    for (int ct = 0; ct < 8; ++ct)
#pragma unroll
      for (int r = 0; r < 4; ++r) {
        const int node = nb + lg * 4 + r;
        if (node < N_NODES) {
          if (ct < 4)
            Aout[(size_t)node * 64 + ct * 16 + l15] = acc[ct][r] + bv[ct];
          else
            Bout[(size_t)node * 64 + (ct - 4) * 16 + l15] = f2bf(acc[ct][r]);
        }
      }
  }
}

// Tree-reduce 2048 per-block partials to g[64].
__global__ void k_gred(const float* __restrict__ P, float* __restrict__ g) {
  __shared__ float red[16][64];
  const int lane = threadIdx.x & 63;
  const int w = threadIdx.x >> 6;
  float m = 0.f;
  for (int r = w; r < NBLK; r += 16)
    m = fmaxf(m, P[(size_t)r * 64 + lane]);
  red[w][lane] = m;
  __syncthreads();
  if (threadIdx.x < 64) {
    float mm = 0.f;
#pragma unroll
    for (int k = 0; k < 16; ++k) mm = fmaxf(mm, red[k][lane]);
    g[lane] = mm;
  }
}

// Head: hidden = relu(h @ Wa_top + gt), gt = ba + g @ Wa_bot;
// out = x + hidden @ Wb + bb.
__global__ __launch_bounds__(TPB, 2)
void k_final(const unsigned short* __restrict__ h, const float* __restrict__ g,
             const float* __restrict__ Wa, const float* __restrict__ ba,
             const float* __restrict__ Wb, const float* __restrict__ bb,
             const float* __restrict__ x, float* __restrict__ out) {
  __shared__ unsigned short lwhi[128 * 72];
  __shared__ unsigned short lwlo[128 * 72];
  __shared__ float sgt[128];
  for (int idx = threadIdx.x; idx < 8192; idx += TPB) {
    const int k = idx >> 7, j = idx & 127;
    const float v = Wa[k * 128 + j];
    const unsigned short hi = f2bf(v);
    lwhi[j * 72 + k] = hi;
    lwlo[j * 72 + k] = f2bf(v - bf2f(hi));
  }
  if (threadIdx.x < 128) {
    const int c = threadIdx.x;
    float s = ba[c];
    for (int k = 0; k < 64; ++k) s = fmaf(g[k], Wa[(64 + k) * 128 + c], s);
    sgt[c] = s;
  }
  __syncthreads();
  const int lane = threadIdx.x & 63;
  const int wav = threadIdx.x >> 6;
  const int l15 = lane & 15, lg = lane >> 4;
  short8 bhi[8][2], blo[8][2];
#pragma unroll
  for (int ct = 0; ct < 8; ++ct)
#pragma unroll
    for (int kk = 0; kk < 2; ++kk) {
      const int off = (ct * 16 + l15) * 72 + kk * 32 + lg * 8;
      bhi[ct][kk] = *(const short8*)&lwhi[off];
      blo[ct][kk] = *(const short8*)&lwlo[off];
    }
  float gtv[8];
#pragma unroll
  for (int ct = 0; ct < 8; ++ct) gtv[ct] = sgt[ct * 16 + l15];
  float wbv[8][3];
#pragma unroll
  for (int ct = 0; ct < 8; ++ct)
#pragma unroll
    for (int jj = 0; jj < 3; ++jj)
      wbv[ct][jj] = Wb[(ct * 16 + l15) * 3 + jj];
  const float bbl = (l15 == 0) ? bb[0] : (l15 == 1 ? bb[1] : bb[2]);
  const int NT = (N_NODES + 63) / 64;
  for (int t = blockIdx.x; t < NT; t += gridDim.x) {
    const int nb = t * 64 + wav * 16;
    const int row = min(nb + l15, N_NODES - 1);
    const unsigned short* hr = h + (size_t)row * 64;
    float4_ acc[8];
#pragma unroll
    for (int ct = 0; ct < 8; ++ct) acc[ct] = (float4_)(0.f);
#pragma unroll
    for (int kk = 0; kk < 2; ++kk) {
      const short8 ahi = *(const short8*)(hr + kk * 32 + lg * 8);
#pragma unroll
      for (int ct = 0; ct < 8; ++ct) {
        acc[ct] = __builtin_amdgcn_mfma_f32_16x16x32_bf16(ahi, bhi[ct][kk], acc[ct], 0, 0, 0);
        acc[ct] = __builtin_amdgcn_mfma_f32_16x16x32_bf16(ahi, blo[ct][kk], acc[ct], 0, 0, 0);
      }
    }
#pragma unroll
    for (int r = 0; r < 4; ++r) {
      float t0 = 0.f, t1 = 0.f, t2 = 0.f;
#pragma unroll
      for (int ct = 0; ct < 8; ++ct) {
        const float hd = fmaxf(acc[ct][r] + gtv[ct], 0.f);
        t0 = fmaf(hd, wbv[ct][0], t0);
        t1 = fmaf(hd, wbv[ct][1], t1);
        t2 = fmaf(hd, wbv[ct][2], t2);
      }
#pragma unroll
      for (int off = 1; off < 16; off <<= 1) {
        t0 += __shfl_xor(t0, off);
        t1 += __shfl_xor(t1, off);
        t2 += __shfl_xor(t2, off);
      }
      const int node = nb + lg * 4 + r;
      if (node < N_NODES && l15 < 3) {
        const float tj = (l15 == 0) ? t0 : (l15 == 1 ? t1 : t2);
        out[(size_t)node * 3 + l15] = x[(size_t)node * 3 + l15] + tj + bbl;
      }
    }
  }
}

extern "C" void kernel_launch(void* const* d_in, const int* in_sizes, int n_in,
                              void* d_out, int out_size, void* d_ws, size_t ws_size,
                              hipStream_t stream) {
  const float* x  = (const float*)d_in[0];
  const int*   ei = (const int*)d_in[1];
  const float* W1 = (const float*)d_in[2];
  const float* b1 = (const float*)d_in[3];
  const float* W2 = (const float*)d_in[4];
  const float* b2 = (const float*)d_in[5];
  const float* W3 = (const float*)d_in[6];
  const float* b3 = (const float*)d_in[7];
  const float* W4 = (const float*)d_in[8];
  const float* b4 = (const float*)d_in[9];
  const float* W5 = (const float*)d_in[10];
  const float* b5 = (const float*)d_in[11];
  const float* Wa = (const float*)d_in[12];
  const float* ba = (const float*)d_in[13];
  const float* Wb = (const float*)d_in[14];
  const float* bb = (const float*)d_in[15];
  float* out = (float*)d_out;

  // ws layout (float words): src[1.6M] | A0[6.4M] | A1[6.4M] |
  // H[3.2M words bf16] | B0[3.2M] | B1[3.2M] | P[2048*64] | g[64]
  float* ws = (float*)d_ws;
  int* srcbuf = (int*)ws;
  float* A0 = ws + 1600000;
  float* A1 = A0 + 6400000;
  unsigned short* H  = (unsigned short*)(A1 + 6400000);
  unsigned short* B0 = H + 6400000;
  unsigned short* B1 = B0 + 6400000;
  float* P = (float*)(B1 + 6400000);
  float* g = P + (size_t)NBLK * 64;

  k_normsrc<<<1024, TPB, 0, stream>>>(ei, srcbuf);
  k_layer1<<<NBLK, TPB, 0, stream>>>(x, W1, b1, A0, B0);
  k_aggr<false><<<NBLK, TPB, 0, stream>>>(srcbuf, A0, B0, H, nullptr);
  k_gemm<<<512, TPB, 0, stream>>>(H, W2, b2, A1, B1);
  k_aggr<false><<<NBLK, TPB, 0, stream>>>(srcbuf, A1, B1, H, nullptr);
  k_gemm<<<512, TPB, 0, stream>>>(H, W3, b3, A0, B0);
  k_aggr<false><<<NBLK, TPB, 0, stream>>>(srcbuf, A0, B0, H, nullptr);
  k_gemm<<<512, TPB, 0, stream>>>(H, W4, b4, A1, B1);
  k_aggr<false><<<NBLK, TPB, 0, stream>>>(srcbuf, A1, B1, H, nullptr);
  k_gemm<<<512, TPB, 0, stream>>>(H, W5, b5, A0, B0);
  k_aggr<true><<<NBLK, TPB, 0, stream>>>(srcbuf, A0, B0, H, P);
  k_gred<<<1, 1024, 0, stream>>>(P, g);
  k_final<<<512, TPB, 0, stream>>>(H, g, Wa, ba, Wb, bb, x, out);
}